// Round 3
// baseline (49.080 us; speedup 1.0000x reference)
//
#include <hip/hip_runtime.h>
#include <hip/hip_bf16.h>
#include <math.h>

#define N_ROWS 8192
#define N_HALF 4096
#define D 128
#define SEGS 8                  // j-split across blocks
#define IBLKS (N_ROWS / 128)    // 64
#define CHUNKS_PER_SEG ((N_ROWS / SEGS) / 128)  // 8
// scale = sqrt(2 * log2(e)) so that zb_i . zb_j = 2*log2(e)*cos -> exp2(dot) = exp(2*cos)
#define ZSCALE 1.6986437717f
#define LN2 0.69314718056f

typedef __attribute__((ext_vector_type(8))) short bfrag;   // 8 bf16 = 4 VGPR
typedef __attribute__((ext_vector_type(4))) float f32x4;

__device__ __forceinline__ float fast_exp2(float x) {
#if __has_builtin(__builtin_amdgcn_exp2f)
    return __builtin_amdgcn_exp2f(x);
#else
    return exp2f(x);
#endif
}

// ---------------- kernel 1: normalize rows; emit scaled bf16 z only ----------------
__global__ __launch_bounds__(256) void normalize_kernel(
    const float* __restrict__ p1, const float* __restrict__ p2,
    ushort* __restrict__ zb)
{
    const int row = blockIdx.x * 4 + (threadIdx.x >> 6);
    const int lane = threadIdx.x & 63;
    const float* src = (row < N_HALF) ? (p1 + (size_t)row * D)
                                      : (p2 + (size_t)(row - N_HALF) * D);
    float2 v = ((const float2*)src)[lane];
    float ss = v.x * v.x + v.y * v.y;
    #pragma unroll
    for (int m = 1; m < 64; m <<= 1) ss += __shfl_xor(ss, m);
    float inv = ZSCALE / fmaxf(sqrtf(ss), 1e-12f);
    __hip_bfloat16 h0 = __float2bfloat16(v.x * inv);
    __hip_bfloat16 h1 = __float2bfloat16(v.y * inv);
    ushort2 u; u.x = *(ushort*)&h0; u.y = *(ushort*)&h1;
    ((ushort2*)(zb + (size_t)row * D))[lane] = u;
}

// ---------------- kernel 2: barrier-free MFMA Gram + exp2 row-sums + positives ----------------
__global__ __launch_bounds__(256, 2) void simloss_mfma(
    const ushort* __restrict__ zb, float* __restrict__ partial,
    float* __restrict__ posv)
{
    __shared__ float red[128][4];     // 2 KB, epilogue only
    const int t = threadIdx.x;
    const int w = t >> 6;             // wave 0..3 -> col quarter
    const int l = t & 63;
    const int l15 = l & 15, lh = l >> 4;
    const int bi = blockIdx.x & 63;
    const int seg = blockIdx.x >> 6;
    const int iBase = bi * 128;
    const int partnerBase = iBase ^ N_HALF;

    // A tile (128 rows x 128 k) in registers (L2-resident source)
    bfrag a[8][4];
    #pragma unroll
    for (int m = 0; m < 8; ++m) {
        const ushort* rp = zb + (size_t)(iBase + m * 16 + l15) * D;
        #pragma unroll
        for (int ks = 0; ks < 4; ++ks)
            a[m][ks] = *(const bfrag*)(rp + ks * 32 + lh * 8);
    }

    float rs[8][4];
    #pragma unroll
    for (int m = 0; m < 8; ++m)
        #pragma unroll
        for (int r = 0; r < 4; ++r) rs[m][r] = 0.0f;

    for (int ch = 0; ch < CHUNKS_PER_SEG; ++ch) {
        const int jBase = seg * (N_ROWS / SEGS) + ch * 128;
        const bool sdiag = (jBase == iBase);
        const bool pdiag = (jBase == partnerBase);

        #pragma unroll
        for (int n = 0; n < 2; ++n) {
            const int cB = w * 32 + n * 16 + l15;        // col-in-chunk this lane owns
            const ushort* jp = zb + (size_t)(jBase + cB) * D + lh * 8;
            bfrag b0 = *(const bfrag*)(jp);
            bfrag b1 = *(const bfrag*)(jp + 32);
            bfrag b2 = *(const bfrag*)(jp + 64);
            bfrag b3 = *(const bfrag*)(jp + 96);

            f32x4 c[8];
            #pragma unroll
            for (int m = 0; m < 8; ++m) { f32x4 z4 = {0.f, 0.f, 0.f, 0.f}; c[m] = z4; }
            #pragma unroll
            for (int m = 0; m < 8; ++m)
                c[m] = __builtin_amdgcn_mfma_f32_16x16x32_bf16(a[m][0], b0, c[m], 0, 0, 0);
            #pragma unroll
            for (int m = 0; m < 8; ++m)
                c[m] = __builtin_amdgcn_mfma_f32_16x16x32_bf16(a[m][1], b1, c[m], 0, 0, 0);
            #pragma unroll
            for (int m = 0; m < 8; ++m)
                c[m] = __builtin_amdgcn_mfma_f32_16x16x32_bf16(a[m][2], b2, c[m], 0, 0, 0);
            #pragma unroll
            for (int m = 0; m < 8; ++m)
                c[m] = __builtin_amdgcn_mfma_f32_16x16x32_bf16(a[m][3], b3, c[m], 0, 0, 0);

            #pragma unroll
            for (int m = 0; m < 8; ++m)
                #pragma unroll
                for (int r = 0; r < 4; ++r) {
                    const int rowLocal = m * 16 + lh * 4 + r;
                    float e = fast_exp2(c[m][r]);
                    rs[m][r] += (sdiag && rowLocal == cB) ? 0.0f : e;
                }

            if (pdiag && (l15 >> 2) == lh) {
                // this lane holds the tile-diagonal element for m = w*2+n at r = l15&3
                const int m = w * 2 + n;
                posv[iBase + m * 16 + l15] = c[m][l15 & 3] * LN2;   // = 2*cos
            }
        }
    }

    // reduce rs over the 16 cols held across l15 lanes (same row group shares lh)
    #pragma unroll
    for (int m = 0; m < 8; ++m)
        #pragma unroll
        for (int r = 0; r < 4; ++r) {
            float v = rs[m][r];
            v += __shfl_xor(v, 1); v += __shfl_xor(v, 2);
            v += __shfl_xor(v, 4); v += __shfl_xor(v, 8);
            rs[m][r] = v;
        }
    if (l15 == 0) {
        #pragma unroll
        for (int m = 0; m < 8; ++m)
            #pragma unroll
            for (int r = 0; r < 4; ++r)
                red[m * 16 + lh * 4 + r][w] = rs[m][r];
    }
    __syncthreads();
    if (t < 128) {
        float v = red[t][0] + red[t][1] + red[t][2] + red[t][3];
        partial[(size_t)seg * N_ROWS + iBase + t] = v;
    }
}

// ---------------- kernel 3: per-row loss + per-block deterministic sum ----------------
__global__ __launch_bounds__(256) void rowloss_kernel(
    const float* __restrict__ partial, const float* __restrict__ posv,
    float* __restrict__ bsum)
{
    const int row = blockIdx.x * 256 + threadIdx.x;
    float denom = 0.0f;
    #pragma unroll
    for (int s = 0; s < SEGS; ++s) denom += partial[(size_t)s * N_ROWS + row];
    float loss = logf(denom) - posv[row];
    #pragma unroll
    for (int m = 1; m < 64; m <<= 1) loss += __shfl_xor(loss, m);
    __shared__ float red[4];
    if ((threadIdx.x & 63) == 0) red[threadIdx.x >> 6] = loss;
    __syncthreads();
    if (threadIdx.x == 0) bsum[blockIdx.x] = red[0] + red[1] + red[2] + red[3];
}

// ---------------- kernel 4: final deterministic reduce of 32 block sums ----------------
__global__ __launch_bounds__(64) void final_reduce(
    const float* __restrict__ bsum, float* __restrict__ out)
{
    const int t = threadIdx.x;
    float s = (t < 32) ? bsum[t] : 0.0f;
    #pragma unroll
    for (int m = 1; m < 64; m <<= 1) s += __shfl_xor(s, m);
    if (t == 0) out[0] = s * (1.0f / (float)N_ROWS);
}

extern "C" void kernel_launch(void* const* d_in, const int* in_sizes, int n_in,
                              void* d_out, int out_size, void* d_ws, size_t ws_size,
                              hipStream_t stream) {
    const float* proj1 = (const float*)d_in[0];
    const float* proj2 = (const float*)d_in[1];
    float* out = (float*)d_out;

    char* ws = (char*)d_ws;
    ushort* zb      = (ushort*)ws;                                  // 2 MB
    float*  partial = (float*)(ws + (size_t)2 * 1024 * 1024);       // 256 KB
    float*  posv    = (float*)(ws + (size_t)2 * 1024 * 1024 + 512 * 1024);  // 32 KB
    float*  bsum    = (float*)(ws + (size_t)2 * 1024 * 1024 + 768 * 1024);  // 128 B

    normalize_kernel<<<N_ROWS / 4, 256, 0, stream>>>(proj1, proj2, zb);
    simloss_mfma<<<IBLKS * SEGS, 256, 0, stream>>>(zb, partial, posv);
    rowloss_kernel<<<N_ROWS / 256, 256, 0, stream>>>(partial, posv, bsum);
    final_reduce<<<1, 64, 0, stream>>>(bsum, out);
}